// Round 11
// baseline (150.483 us; speedup 1.0000x reference)
//
#include <hip/hip_runtime.h>
#include <math.h>

// Problem constants (from reference)
constexpr int Bsz = 16, Nn = 1024, Cc = 16, Ss = 8;
constexpr int BN = Bsz * Nn;            // 16384 nodes total
constexpr int EQ = 16;                  // nodes per block (emb kernel)
constexpr int CQ = 32;                  // nodes per block (conv kernel)

typedef __attribute__((ext_vector_type(8))) short bf16x8;
typedef __attribute__((ext_vector_type(4))) float f32x4;
typedef __attribute__((ext_vector_type(4))) unsigned short u16x4;

__device__ inline unsigned short f2bf_rne(float x) {
    unsigned u = __builtin_bit_cast(unsigned, x);
    unsigned r = (u + 0x7FFFu + ((u >> 16) & 1u)) >> 16;
    return (unsigned short)r;
}
__device__ inline float bf2f(unsigned short h) {
    unsigned u = ((unsigned)h) << 16;
    return __builtin_bit_cast(float, u);
}
// fast tanh via v_exp_f32 (adds <~2e-6 abs error; bf16 floor dominates)
__device__ inline float fast_tanh(float x) {
    const float ax = fabsf(x);
    const float t  = __expf(-2.f * ax);
    const float r  = __fdividef(1.f - t, 1.f + t);
    return copysignf(r, x);
}

// ---------------------------------------------------------------------------
// Kernel 0: pack W_parent [256][256] -> fragment-major bf16 (32 blocks).
// ---------------------------------------------------------------------------
__global__ __launch_bounds__(256) void pack_wp_kernel(
    const float* __restrict__ Wp, unsigned short* __restrict__ wpq)
{
    const int t = blockIdx.x * 256 + threadIdx.x;    // 0..8191
    const int col = t & 255;
    const int gg  = (t >> 8) & 3;
    const int kb  = t >> 10;                          // 0..7
    const size_t dst = (size_t)t * 8;
    #pragma unroll
    for (int i = 0; i < 8; ++i)
        wpq[dst + i] = f2bf_rne(Wp[(size_t)(kb * 32 + gg * 8 + i) * 256 + col]);
}

// ---------------------------------------------------------------------------
// Kernel 1: fused embeddings + parent projection via MFMA, 16 rows/block.
// Balanced phase 1: half-wave 0 = type row + tokens 0-3, half-wave 1 =
// tokens 4-7; cross-half shfl_xor(32) combines the token sum.
// Blocks 0..191 additionally pack the conv weights (consumed by conv1).
// ---------------------------------------------------------------------------
__global__ __launch_bounds__(256, 4) void emb_mfma_kernel(
    const int* __restrict__ node_type, const int* __restrict__ node_tokens,
    const float* __restrict__ type_table, const float* __restrict__ token_table,
    const unsigned short* __restrict__ wpq,   // packed W_parent
    const float* __restrict__ bp,
    unsigned short* __restrict__ outh,        // bf16 nodes
    const float* __restrict__ conv_w,         // [2][768][256] (pack fold)
    unsigned short* __restrict__ whi)         // packed conv W out
{
    constexpr int AP = 264;                   // padded stride (bf16 elems)
    __shared__ unsigned short A[EQ][AP];      // 8.25 KB

    const int tid  = threadIdx.x;
    const int lane = tid & 63;
    const int w    = tid >> 6;
    const int g0   = blockIdx.x * EQ;

    // phase 1: build bf16 emb tile (4 rows per wave, balanced halves)
    {
        const int q    = lane & 31;           // float4 chunk (0..31)
        const int half = lane >> 5;           // 0/1
        #pragma unroll
        for (int it = 0; it < 4; ++it) {
            const int r = w * 4 + it;
            const int gnode = g0 + r;
            f32x4 acc = (f32x4){0.f, 0.f, 0.f, 0.f};
            #pragma unroll
            for (int s = 0; s < 4; ++s) {
                const int tok = node_tokens[gnode * Ss + half * 4 + s];
                const f32x4 v = *reinterpret_cast<const f32x4*>(
                    token_table + (size_t)tok * 128 + q * 4);
                acc += v;
            }
            f32x4 tot;
            tot.x = acc.x + __shfl_xor(acc.x, 32);
            tot.y = acc.y + __shfl_xor(acc.y, 32);
            tot.z = acc.z + __shfl_xor(acc.z, 32);
            tot.w = acc.w + __shfl_xor(acc.w, 32);
            if (half == 0) {
                const int tt = node_type[gnode];
                const f32x4 tv = *reinterpret_cast<const f32x4*>(
                    type_table + (size_t)tt * 128 + q * 4);
                u16x4 s0;
                s0.x = f2bf_rne(tv.x); s0.y = f2bf_rne(tv.y);
                s0.z = f2bf_rne(tv.z); s0.w = f2bf_rne(tv.w);
                *reinterpret_cast<u16x4*>(&A[r][q * 4]) = s0;
            } else {
                u16x4 s1;
                s1.x = f2bf_rne(tot.x); s1.y = f2bf_rne(tot.y);
                s1.z = f2bf_rne(tot.z); s1.w = f2bf_rne(tot.w);
                *reinterpret_cast<u16x4*>(&A[r][128 + q * 4]) = s1;
            }
        }
    }
    __syncthreads();

    // phase 2: MFMA GEMM [16 x 256] @ [256 x 256], 2-deep B pipeline
    const int colg = w * 64;
    const int rr   = lane & 15;
    const int g    = lane >> 4;

    const unsigned short* pwh = wpq + ((size_t)(g * 256 + colg + rr)) * 8;

    f32x4 acc[4];
    #pragma unroll
    for (int f = 0; f < 4; ++f) acc[f] = (f32x4){0.f, 0.f, 0.f, 0.f};

    bf16x8 bA[4], bB[4];
    #pragma unroll
    for (int f = 0; f < 4; ++f)
        bA[f] = *reinterpret_cast<const bf16x8*>(pwh + f * 128);

    for (int kb = 0; kb < 8; kb += 2) {
        {
            const int o1 = (kb + 1) * 8192;
            #pragma unroll
            for (int f = 0; f < 4; ++f)
                bB[f] = *reinterpret_cast<const bf16x8*>(pwh + o1 + f * 128);
        }
        {
            const int k0 = kb * 32 + g * 8;
            const bf16x8 ah = *reinterpret_cast<const bf16x8*>(&A[rr][k0]);
            #pragma unroll
            for (int f = 0; f < 4; ++f)
                acc[f] = __builtin_amdgcn_mfma_f32_16x16x32_bf16(ah, bA[f], acc[f], 0, 0, 0);
        }
        if (kb + 2 < 8) {
            const int o2 = (kb + 2) * 8192;
            #pragma unroll
            for (int f = 0; f < 4; ++f)
                bA[f] = *reinterpret_cast<const bf16x8*>(pwh + o2 + f * 128);
        }
        {
            const int k0 = (kb + 1) * 32 + g * 8;
            const bf16x8 ah = *reinterpret_cast<const bf16x8*>(&A[rr][k0]);
            #pragma unroll
            for (int f = 0; f < 4; ++f)
                acc[f] = __builtin_amdgcn_mfma_f32_16x16x32_bf16(ah, bB[f], acc[f], 0, 0, 0);
        }
    }

    // epilogue: D row = g*4+i, col = colg + f*16 + rr  (bf16 store)
    #pragma unroll
    for (int f = 0; f < 4; ++f) {
        const int col = colg + f * 16 + rr;
        const float bv = bp[col];
        #pragma unroll
        for (int i = 0; i < 4; ++i) {
            const int row = g * 4 + i;
            outh[(size_t)(g0 + row) * 256 + col] = f2bf_rne(acc[f][i] + bv);
        }
    }

    // pack fold: blocks 0..191 pack the conv weights (needed by conv1)
    if (blockIdx.x < 192) {
        const int t = blockIdx.x * 256 + tid;            // 0..49151
        const int col = t & 255;
        const int gg  = (t >> 8) & 3;
        const int kb  = (t >> 10) % 24;
        const int l   = t / (24 * 4 * 256);
        const float* W = conv_w + (size_t)l * 768 * 256;
        const size_t dst = (size_t)t * 8;
        #pragma unroll
        for (int i = 0; i < 8; ++i)
            whi[dst + i] = f2bf_rne(W[(size_t)(kb * 32 + gg * 8 + i) * 256 + col]);
    }
}

// ---------------------------------------------------------------------------
// Kernel 2: tree-conv layer, pure-bf16 MFMA. 32 rows/block, 512 threads.
// FUSE=1: + fused score/sigmoid/weighted-partial epilogue + ticket-based
// final reduce (last block per batch sums the 32 partial rows -> code).
// ---------------------------------------------------------------------------
template<int FUSE>
__global__ __launch_bounds__(512, 4) void conv_mfma_kernel(
    const unsigned short* __restrict__ in_h,  // bf16 nodes [BN][256]
    const int* __restrict__ children_index,
    const unsigned short* __restrict__ whi,   // layer offset pre-applied
    const float* __restrict__ bias,           // [256]
    unsigned short* __restrict__ out_h,       // FUSE=0
    float* __restrict__ out_f,                // FUSE=1 (final nodes, fp32)
    const int* __restrict__ node_type,        // FUSE only
    const float* __restrict__ attn_a,         // FUSE only
    float* __restrict__ partial,              // FUSE only: [512][256]
    float* __restrict__ code,                 // FUSE only: [16][256]
    int* __restrict__ cnt)                    // FUSE only: [16]
{
    constexpr int AP = 776;                   // padded k-stride (bf16 elems)
    __shared__ unsigned short Ahi[CQ][AP];    // 48.5 KB
    __shared__ unsigned short idx_s[CQ][Cc];  // 1 KB
    __shared__ float etar_s[CQ][Cc];          // 2 KB
    __shared__ float etal_s[CQ][Cc];          // 2 KB

    const int tid = threadIdx.x;

    // XCD swizzle: 32 blocks per batch; batch b -> XCD b%8.
    const int P = blockIdx.x;
    const int xx = P & 7;
    const int rst = P >> 3;
    const int j = rst & 31;
    const int yy = rst >> 5;
    const int batch = xx + 8 * yy;
    const int g0 = batch * Nn + j * CQ;
    const unsigned short* inb = in_h + (size_t)batch * Nn * 256;

    // phase 1: children indices + TBCNN coefficients (one (r,c)/thread)
    {
        const int r = tid >> 4, c = tid & 15;
        idx_s[r][c] = (unsigned short)children_index[(size_t)(g0 + r) * Cc + c];
    }
    __syncthreads();
    {
        const int r = tid >> 4, c = tid & 15;
        int ns = 0;
        #pragma unroll
        for (int q = 0; q < Cc; ++q) ns += (idx_s[r][q] > 0) ? 1 : 0;
        const bool cm = idx_s[r][c] > 0;
        float er;
        if (ns == 1) {
            er = (c == 0) ? 0.5f : 0.f;       // reference's "singles" quirk
        } else {
            const float denom = (float)((ns - 1 > 1) ? (ns - 1) : 1);
            er = (float)c / denom;
        }
        etar_s[r][c] = cm ? er : 0.f;
        etal_s[r][c] = cm ? (1.f - er) : 0.f;
    }
    __syncthreads();

    // phase 2: bf16 gather + vector mix -> bf16 LDS tile [32][768]
    {
        const int q = tid & 63;               // 4-elem chunk within row
        const int rgrp = tid >> 6;            // wave id (0..7)
        #pragma unroll
        for (int rr4 = 0; rr4 < 4; ++rr4) {
            const int r = rgrp * 4 + rr4;
            const u16x4 m0h = *reinterpret_cast<const u16x4*>(
                in_h + (size_t)(g0 + r) * 256 + q * 4);
            f32x4 m1 = (f32x4){0.f, 0.f, 0.f, 0.f};
            f32x4 m2 = (f32x4){0.f, 0.f, 0.f, 0.f};
            #pragma unroll
            for (int c = 0; c < Cc; ++c) {
                const int ci = idx_s[r][c];
                const u16x4 vh = *reinterpret_cast<const u16x4*>(
                    inb + (size_t)ci * 256 + q * 4);
                f32x4 vf;
                vf.x = bf2f(vh.x); vf.y = bf2f(vh.y);
                vf.z = bf2f(vh.z); vf.w = bf2f(vh.w);
                m1 += etar_s[r][c] * vf;      // v_pk_fma_f32
                m2 += etal_s[r][c] * vf;
            }
            u16x4 s1, s2;
            s1.x = f2bf_rne(m1.x); s1.y = f2bf_rne(m1.y);
            s1.z = f2bf_rne(m1.z); s1.w = f2bf_rne(m1.w);
            s2.x = f2bf_rne(m2.x); s2.y = f2bf_rne(m2.y);
            s2.z = f2bf_rne(m2.z); s2.w = f2bf_rne(m2.w);
            *reinterpret_cast<u16x4*>(&Ahi[r][q * 4])       = m0h;
            *reinterpret_cast<u16x4*>(&Ahi[r][256 + q * 4]) = s1;
            *reinterpret_cast<u16x4*>(&Ahi[r][512 + q * 4]) = s2;
        }
    }
    __syncthreads();

    // phase 3: MFMA GEMM [32 x 768] @ [768 x 256], 2-deep B pipeline.
    const int lane = tid & 63;
    const int w    = tid >> 6;
    const int colg = w * 32;
    const int rr   = lane & 15;
    const int g    = lane >> 4;

    const unsigned short* pwh = whi + ((size_t)(g * 256 + colg + rr)) * 8;

    f32x4 acc[2][2];
    #pragma unroll
    for (int t = 0; t < 2; ++t)
        #pragma unroll
        for (int f = 0; f < 2; ++f) acc[t][f] = (f32x4){0.f, 0.f, 0.f, 0.f};

    bf16x8 bA[2], bB[2];
    #pragma unroll
    for (int f = 0; f < 2; ++f)
        bA[f] = *reinterpret_cast<const bf16x8*>(pwh + f * 128);

    __builtin_amdgcn_s_setprio(1);
    for (int kb = 0; kb < 24; kb += 2) {
        {
            const int o1 = (kb + 1) * 8192;
            #pragma unroll
            for (int f = 0; f < 2; ++f)
                bB[f] = *reinterpret_cast<const bf16x8*>(pwh + o1 + f * 128);
        }
        {
            const int k0 = kb * 32 + g * 8;
            const bf16x8 a0 = *reinterpret_cast<const bf16x8*>(&Ahi[rr][k0]);
            const bf16x8 a1 = *reinterpret_cast<const bf16x8*>(&Ahi[16 + rr][k0]);
            #pragma unroll
            for (int f = 0; f < 2; ++f) {
                acc[0][f] = __builtin_amdgcn_mfma_f32_16x16x32_bf16(a0, bA[f], acc[0][f], 0, 0, 0);
                acc[1][f] = __builtin_amdgcn_mfma_f32_16x16x32_bf16(a1, bA[f], acc[1][f], 0, 0, 0);
            }
        }
        if (kb + 2 < 24) {
            const int o2 = (kb + 2) * 8192;
            #pragma unroll
            for (int f = 0; f < 2; ++f)
                bA[f] = *reinterpret_cast<const bf16x8*>(pwh + o2 + f * 128);
        }
        {
            const int k0 = (kb + 1) * 32 + g * 8;
            const bf16x8 a0 = *reinterpret_cast<const bf16x8*>(&Ahi[rr][k0]);
            const bf16x8 a1 = *reinterpret_cast<const bf16x8*>(&Ahi[16 + rr][k0]);
            #pragma unroll
            for (int f = 0; f < 2; ++f) {
                acc[0][f] = __builtin_amdgcn_mfma_f32_16x16x32_bf16(a0, bB[f], acc[0][f], 0, 0, 0);
                acc[1][f] = __builtin_amdgcn_mfma_f32_16x16x32_bf16(a1, bB[f], acc[1][f], 0, 0, 0);
            }
        }
    }
    __builtin_amdgcn_s_setprio(0);

    // epilogue: D row = t*16 + g*4+i, col = colg + f*16 + rr
    float nd[2][2][4];
    #pragma unroll
    for (int t = 0; t < 2; ++t)
        #pragma unroll
        for (int f = 0; f < 2; ++f) {
            const int col = colg + f * 16 + rr;
            const float bv = bias[col];
            #pragma unroll
            for (int i = 0; i < 4; ++i) {
                const int row = t * 16 + g * 4 + i;
                const float v = fast_tanh(acc[t][f][i] + bv);
                nd[t][f][i] = v;
                if (FUSE) out_f[(size_t)(g0 + row) * 256 + col] = v;
                else      out_h[(size_t)(g0 + row) * 256 + col] = f2bf_rne(v);
            }
        }

    if constexpr (FUSE) {
        __shared__ float sc_lds[8][CQ];
        __shared__ float wm_lds[CQ];
        __shared__ int   win_s;
        __shared__ float red_s[2][256];

        // --- attention score: per-row dot(nodes_row, a) ---
        float av[2];
        #pragma unroll
        for (int f = 0; f < 2; ++f) av[f] = attn_a[colg + f * 16 + rr];

        float s[2][4];
        #pragma unroll
        for (int t = 0; t < 2; ++t)
            #pragma unroll
            for (int i = 0; i < 4; ++i) {
                float v = 0.f;
                #pragma unroll
                for (int f = 0; f < 2; ++f) v = fmaf(nd[t][f][i], av[f], v);
                s[t][i] = v;
            }
        #pragma unroll
        for (int off = 1; off < 16; off <<= 1)
            #pragma unroll
            for (int t = 0; t < 2; ++t)
                #pragma unroll
                for (int i = 0; i < 4; ++i)
                    s[t][i] += __shfl_xor(s[t][i], off, 64);
        if (rr == 0) {
            #pragma unroll
            for (int t = 0; t < 2; ++t)
                #pragma unroll
                for (int i = 0; i < 4; ++i)
                    sc_lds[w][t * 16 + g * 4 + i] = s[t][i];
        }
        __syncthreads();
        if (tid < CQ) {
            float sc = 0.f;
            #pragma unroll
            for (int ww = 0; ww < 8; ++ww) sc += sc_lds[ww][tid];
            float wmv = 0.f;
            if (node_type[g0 + tid] != 0)
                wmv = __fdividef(1.f, 1.f + __expf(-sc));
            wm_lds[tid] = wmv;
        }
        __syncthreads();

        // --- weighted column-sum over the block's 32 rows ---
        float qf[2];
        #pragma unroll
        for (int f = 0; f < 2; ++f) {
            float v = 0.f;
            #pragma unroll
            for (int t = 0; t < 2; ++t)
                #pragma unroll
                for (int i = 0; i < 4; ++i)
                    v = fmaf(wm_lds[t * 16 + g * 4 + i], nd[t][f][i], v);
            qf[f] = v;
        }
        #pragma unroll
        for (int f = 0; f < 2; ++f) {
            qf[f] += __shfl_xor(qf[f], 16, 64);
            qf[f] += __shfl_xor(qf[f], 32, 64);
        }
        if (g == 0) {
            const int pidx = batch * 32 + j;
            #pragma unroll
            for (int f = 0; f < 2; ++f)
                partial[(size_t)pidx * 256 + colg + f * 16 + rr] = qf[f];
        }

        // --- ticket: last block of this batch reduces partial -> code ---
        __threadfence();                      // make partial device-visible
        __syncthreads();
        if (tid == 0) {
            const int old = __hip_atomic_fetch_add(&cnt[batch], 1,
                                __ATOMIC_ACQ_REL, __HIP_MEMORY_SCOPE_AGENT);
            win_s = (old == 31);
        }
        __syncthreads();
        if (win_s) {
            const int o  = tid & 255;
            const int hh = tid >> 8;          // 0/1: rows hh*16..hh*16+15
            float a2 = 0.f;
            #pragma unroll
            for (int c = 0; c < 16; ++c) {
                const int rowp = batch * 32 + hh * 16 + c;
                a2 += __hip_atomic_load(&partial[(size_t)rowp * 256 + o],
                                        __ATOMIC_RELAXED, __HIP_MEMORY_SCOPE_AGENT);
            }
            red_s[hh][o] = a2;
            __syncthreads();
            if (tid < 256)
                code[batch * 256 + tid] = (red_s[0][tid] + red_s[1][tid]) * (1.f / 1024.f);
        }
    }
}

// ---------------------------------------------------------------------------
extern "C" void kernel_launch(void* const* d_in, const int* in_sizes, int n_in,
                              void* d_out, int out_size, void* d_ws, size_t ws_size,
                              hipStream_t stream)
{
    const int*   node_type   = (const int*)d_in[0];
    const int*   node_tokens = (const int*)d_in[1];
    const int*   children    = (const int*)d_in[2];
    const float* type_table  = (const float*)d_in[3];
    const float* token_table = (const float*)d_in[4];
    const float* Wp          = (const float*)d_in[5];
    const float* bp          = (const float*)d_in[6];
    const float* conv_w      = (const float*)d_in[7];
    const float* conv_b      = (const float*)d_in[8];
    const float* attn_a      = (const float*)d_in[9];

    float* out    = (float*)d_out;
    float* code   = out;                  // [B*O] = 4096
    float* nodesF = out + 4096;           // [BN*256] fp32 (final nodes output)

    unsigned short* nodes0 = (unsigned short*)d_ws;      // bf16 [BN*256]
    unsigned short* nodes1 = nodes0 + (size_t)BN * 256;  // bf16 [BN*256]
    float* partial = (float*)(nodes1 + (size_t)BN * 256);      // [512*256]
    unsigned short* whi = (unsigned short*)(partial + 512 * 256);  // [2][196608]
    unsigned short* wpq = whi + 2 * 196608;   // [65536]
    int* cnt = (int*)(wpq + 65536);           // [16]

    constexpr int LSTRIDE = 196608;           // packed shorts per layer

    hipMemsetAsync(cnt, 0, 16 * sizeof(int), stream);

    pack_wp_kernel<<<32, 256, 0, stream>>>(Wp, wpq);

    emb_mfma_kernel<<<BN / EQ, 256, 0, stream>>>(
        node_type, node_tokens, type_table, token_table, wpq, bp, nodes0,
        conv_w, whi);

    conv_mfma_kernel<0><<<BN / CQ, 512, 0, stream>>>(
        nodes0, children, whi, conv_b, nodes1,
        nullptr, nullptr, nullptr, nullptr, nullptr, nullptr);

    conv_mfma_kernel<1><<<BN / CQ, 512, 0, stream>>>(
        nodes1, children, whi + LSTRIDE, conv_b + 256, nullptr,
        nodesF, node_type, attn_a, partial, code, cnt);
}

// Round 12
// 70.549 us; speedup vs baseline: 2.1330x; 2.1330x over previous
//
#include <hip/hip_runtime.h>
#include <math.h>

// Problem constants (from reference)
constexpr int Bsz = 16, Nn = 1024, Cc = 16, Ss = 8;
constexpr int BN = Bsz * Nn;            // 16384 nodes total
constexpr int EQ = 16;                  // nodes per block (emb kernel)
constexpr int CQ = 32;                  // nodes per block (conv kernel)

typedef __attribute__((ext_vector_type(8))) short bf16x8;
typedef __attribute__((ext_vector_type(4))) float f32x4;
typedef __attribute__((ext_vector_type(4))) unsigned short u16x4;

__device__ inline unsigned short f2bf_rne(float x) {
    unsigned u = __builtin_bit_cast(unsigned, x);
    unsigned r = (u + 0x7FFFu + ((u >> 16) & 1u)) >> 16;
    return (unsigned short)r;
}
__device__ inline float bf2f(unsigned short h) {
    unsigned u = ((unsigned)h) << 16;
    return __builtin_bit_cast(float, u);
}
// fast tanh via v_exp_f32 (adds <~2e-6 abs error; bf16 floor dominates)
__device__ inline float fast_tanh(float x) {
    const float ax = fabsf(x);
    const float t  = __expf(-2.f * ax);
    const float r  = __fdividef(1.f - t, 1.f + t);
    return copysignf(r, x);
}

// ---------------------------------------------------------------------------
// Kernel 0: pack W_parent [256][256] -> fragment-major bf16 (32 blocks).
// ---------------------------------------------------------------------------
__global__ __launch_bounds__(256) void pack_wp_kernel(
    const float* __restrict__ Wp, unsigned short* __restrict__ wpq)
{
    const int t = blockIdx.x * 256 + threadIdx.x;    // 0..8191
    const int col = t & 255;
    const int gg  = (t >> 8) & 3;
    const int kb  = t >> 10;                          // 0..7
    const size_t dst = (size_t)t * 8;
    #pragma unroll
    for (int i = 0; i < 8; ++i)
        wpq[dst + i] = f2bf_rne(Wp[(size_t)(kb * 32 + gg * 8 + i) * 256 + col]);
}

// ---------------------------------------------------------------------------
// Kernel 1: fused embeddings + parent projection via MFMA, 16 rows/block.
// Balanced phase 1: half-wave 0 = type row + tokens 0-3, half-wave 1 =
// tokens 4-7; cross-half shfl_xor(32) combines the token sum.
// Blocks 0..191 additionally pack the conv weights (consumed by conv1).
// ---------------------------------------------------------------------------
__global__ __launch_bounds__(256, 4) void emb_mfma_kernel(
    const int* __restrict__ node_type, const int* __restrict__ node_tokens,
    const float* __restrict__ type_table, const float* __restrict__ token_table,
    const unsigned short* __restrict__ wpq,   // packed W_parent
    const float* __restrict__ bp,
    unsigned short* __restrict__ outh,        // bf16 nodes
    const float* __restrict__ conv_w,         // [2][768][256] (pack fold)
    unsigned short* __restrict__ whi)         // packed conv W out
{
    constexpr int AP = 264;                   // padded stride (bf16 elems)
    __shared__ unsigned short A[EQ][AP];      // 8.25 KB

    const int tid  = threadIdx.x;
    const int lane = tid & 63;
    const int w    = tid >> 6;
    const int g0   = blockIdx.x * EQ;

    // phase 1: build bf16 emb tile (4 rows per wave, balanced halves)
    {
        const int q    = lane & 31;           // float4 chunk (0..31)
        const int half = lane >> 5;           // 0/1
        #pragma unroll
        for (int it = 0; it < 4; ++it) {
            const int r = w * 4 + it;
            const int gnode = g0 + r;
            f32x4 acc = (f32x4){0.f, 0.f, 0.f, 0.f};
            #pragma unroll
            for (int s = 0; s < 4; ++s) {
                const int tok = node_tokens[gnode * Ss + half * 4 + s];
                const f32x4 v = *reinterpret_cast<const f32x4*>(
                    token_table + (size_t)tok * 128 + q * 4);
                acc += v;
            }
            f32x4 tot;
            tot.x = acc.x + __shfl_xor(acc.x, 32);
            tot.y = acc.y + __shfl_xor(acc.y, 32);
            tot.z = acc.z + __shfl_xor(acc.z, 32);
            tot.w = acc.w + __shfl_xor(acc.w, 32);
            if (half == 0) {
                const int tt = node_type[gnode];
                const f32x4 tv = *reinterpret_cast<const f32x4*>(
                    type_table + (size_t)tt * 128 + q * 4);
                u16x4 s0;
                s0.x = f2bf_rne(tv.x); s0.y = f2bf_rne(tv.y);
                s0.z = f2bf_rne(tv.z); s0.w = f2bf_rne(tv.w);
                *reinterpret_cast<u16x4*>(&A[r][q * 4]) = s0;
            } else {
                u16x4 s1;
                s1.x = f2bf_rne(tot.x); s1.y = f2bf_rne(tot.y);
                s1.z = f2bf_rne(tot.z); s1.w = f2bf_rne(tot.w);
                *reinterpret_cast<u16x4*>(&A[r][128 + q * 4]) = s1;
            }
        }
    }
    __syncthreads();

    // phase 2: MFMA GEMM [16 x 256] @ [256 x 256], 2-deep B pipeline
    const int colg = w * 64;
    const int rr   = lane & 15;
    const int g    = lane >> 4;

    const unsigned short* pwh = wpq + ((size_t)(g * 256 + colg + rr)) * 8;

    f32x4 acc[4];
    #pragma unroll
    for (int f = 0; f < 4; ++f) acc[f] = (f32x4){0.f, 0.f, 0.f, 0.f};

    bf16x8 bA[4], bB[4];
    #pragma unroll
    for (int f = 0; f < 4; ++f)
        bA[f] = *reinterpret_cast<const bf16x8*>(pwh + f * 128);

    for (int kb = 0; kb < 8; kb += 2) {
        {
            const int o1 = (kb + 1) * 8192;
            #pragma unroll
            for (int f = 0; f < 4; ++f)
                bB[f] = *reinterpret_cast<const bf16x8*>(pwh + o1 + f * 128);
        }
        {
            const int k0 = kb * 32 + g * 8;
            const bf16x8 ah = *reinterpret_cast<const bf16x8*>(&A[rr][k0]);
            #pragma unroll
            for (int f = 0; f < 4; ++f)
                acc[f] = __builtin_amdgcn_mfma_f32_16x16x32_bf16(ah, bA[f], acc[f], 0, 0, 0);
        }
        if (kb + 2 < 8) {
            const int o2 = (kb + 2) * 8192;
            #pragma unroll
            for (int f = 0; f < 4; ++f)
                bA[f] = *reinterpret_cast<const bf16x8*>(pwh + o2 + f * 128);
        }
        {
            const int k0 = (kb + 1) * 32 + g * 8;
            const bf16x8 ah = *reinterpret_cast<const bf16x8*>(&A[rr][k0]);
            #pragma unroll
            for (int f = 0; f < 4; ++f)
                acc[f] = __builtin_amdgcn_mfma_f32_16x16x32_bf16(ah, bB[f], acc[f], 0, 0, 0);
        }
    }

    // epilogue: D row = g*4+i, col = colg + f*16 + rr  (bf16 store)
    #pragma unroll
    for (int f = 0; f < 4; ++f) {
        const int col = colg + f * 16 + rr;
        const float bv = bp[col];
        #pragma unroll
        for (int i = 0; i < 4; ++i) {
            const int row = g * 4 + i;
            outh[(size_t)(g0 + row) * 256 + col] = f2bf_rne(acc[f][i] + bv);
        }
    }

    // pack fold: blocks 0..191 pack the conv weights (needed by conv1)
    if (blockIdx.x < 192) {
        const int t = blockIdx.x * 256 + tid;            // 0..49151
        const int col = t & 255;
        const int gg  = (t >> 8) & 3;
        const int kb  = (t >> 10) % 24;
        const int l   = t / (24 * 4 * 256);
        const float* W = conv_w + (size_t)l * 768 * 256;
        const size_t dst = (size_t)t * 8;
        #pragma unroll
        for (int i = 0; i < 8; ++i)
            whi[dst + i] = f2bf_rne(W[(size_t)(kb * 32 + gg * 8 + i) * 256 + col]);
    }
}

// ---------------------------------------------------------------------------
// Kernel 2: tree-conv layer, pure-bf16 MFMA. 32 rows/block, 512 threads
// (8 waves, each owns 32 output cols). bf16 node input. fp32 eta, fast tanh.
// FUSE=0: bf16 output. FUSE=1: fp32 output (d_out) + fused
// score/sigmoid/weighted-partial epilogue. (R10 structure — no fences.)
// ---------------------------------------------------------------------------
template<int FUSE>
__global__ __launch_bounds__(512, 4) void conv_mfma_kernel(
    const unsigned short* __restrict__ in_h,  // bf16 nodes [BN][256]
    const int* __restrict__ children_index,
    const unsigned short* __restrict__ whi,   // layer offset pre-applied
    const float* __restrict__ bias,           // [256]
    unsigned short* __restrict__ out_h,       // FUSE=0
    float* __restrict__ out_f,                // FUSE=1 (final nodes, fp32)
    const int* __restrict__ node_type,        // FUSE only
    const float* __restrict__ attn_a,         // FUSE only
    float* __restrict__ partial)              // FUSE only: [512][256]
{
    constexpr int AP = 776;                   // padded k-stride (bf16 elems)
    __shared__ unsigned short Ahi[CQ][AP];    // 48.5 KB
    __shared__ unsigned short idx_s[CQ][Cc];  // 1 KB
    __shared__ float etar_s[CQ][Cc];          // 2 KB
    __shared__ float etal_s[CQ][Cc];          // 2 KB
    __shared__ float sc_lds[8][CQ];           // 1 KB (FUSE)
    __shared__ float wm_lds[CQ];              // 128 B (FUSE)

    const int tid = threadIdx.x;

    // XCD swizzle: 32 blocks per batch; batch b -> XCD b%8.
    const int P = blockIdx.x;
    const int xx = P & 7;
    const int rst = P >> 3;
    const int j = rst & 31;
    const int yy = rst >> 5;
    const int batch = xx + 8 * yy;
    const int g0 = batch * Nn + j * CQ;
    const unsigned short* inb = in_h + (size_t)batch * Nn * 256;

    // phase 1: children indices + TBCNN coefficients (one (r,c)/thread)
    {
        const int r = tid >> 4, c = tid & 15;
        idx_s[r][c] = (unsigned short)children_index[(size_t)(g0 + r) * Cc + c];
    }
    __syncthreads();
    {
        const int r = tid >> 4, c = tid & 15;
        int ns = 0;
        #pragma unroll
        for (int q = 0; q < Cc; ++q) ns += (idx_s[r][q] > 0) ? 1 : 0;
        const bool cm = idx_s[r][c] > 0;
        float er;
        if (ns == 1) {
            er = (c == 0) ? 0.5f : 0.f;       // reference's "singles" quirk
        } else {
            const float denom = (float)((ns - 1 > 1) ? (ns - 1) : 1);
            er = (float)c / denom;
        }
        etar_s[r][c] = cm ? er : 0.f;
        etal_s[r][c] = cm ? (1.f - er) : 0.f;
    }
    __syncthreads();

    // phase 2: bf16 gather + mix -> bf16 LDS tile [32][768]
    {
        const int q = tid & 63;               // 4-elem chunk within row
        const int rgrp = tid >> 6;            // wave id (0..7)
        #pragma unroll
        for (int rr4 = 0; rr4 < 4; ++rr4) {
            const int r = rgrp * 4 + rr4;
            const u16x4 m0h = *reinterpret_cast<const u16x4*>(
                in_h + (size_t)(g0 + r) * 256 + q * 4);
            float4 m1 = {0.f, 0.f, 0.f, 0.f};
            float4 m2 = {0.f, 0.f, 0.f, 0.f};
            #pragma unroll
            for (int c = 0; c < Cc; ++c) {
                const int ci = idx_s[r][c];
                const u16x4 vh = *reinterpret_cast<const u16x4*>(
                    inb + (size_t)ci * 256 + q * 4);
                const float vx = bf2f(vh.x), vy = bf2f(vh.y);
                const float vz = bf2f(vh.z), vw = bf2f(vh.w);
                const float er = etar_s[r][c];
                const float el = etal_s[r][c];
                m1.x = fmaf(er, vx, m1.x); m1.y = fmaf(er, vy, m1.y);
                m1.z = fmaf(er, vz, m1.z); m1.w = fmaf(er, vw, m1.w);
                m2.x = fmaf(el, vx, m2.x); m2.y = fmaf(el, vy, m2.y);
                m2.z = fmaf(el, vz, m2.z); m2.w = fmaf(el, vw, m2.w);
            }
            u16x4 s1, s2;
            s1.x = f2bf_rne(m1.x); s1.y = f2bf_rne(m1.y);
            s1.z = f2bf_rne(m1.z); s1.w = f2bf_rne(m1.w);
            s2.x = f2bf_rne(m2.x); s2.y = f2bf_rne(m2.y);
            s2.z = f2bf_rne(m2.z); s2.w = f2bf_rne(m2.w);
            *reinterpret_cast<u16x4*>(&Ahi[r][q * 4])       = m0h;
            *reinterpret_cast<u16x4*>(&Ahi[r][256 + q * 4]) = s1;
            *reinterpret_cast<u16x4*>(&Ahi[r][512 + q * 4]) = s2;
        }
    }
    __syncthreads();

    // phase 3: MFMA GEMM [32 x 768] @ [768 x 256], 2-deep B pipeline.
    const int lane = tid & 63;
    const int w    = tid >> 6;
    const int colg = w * 32;
    const int rr   = lane & 15;
    const int g    = lane >> 4;

    const unsigned short* pwh = whi + ((size_t)(g * 256 + colg + rr)) * 8;

    f32x4 acc[2][2];
    #pragma unroll
    for (int t = 0; t < 2; ++t)
        #pragma unroll
        for (int f = 0; f < 2; ++f) acc[t][f] = (f32x4){0.f, 0.f, 0.f, 0.f};

    bf16x8 bA[2], bB[2];
    #pragma unroll
    for (int f = 0; f < 2; ++f)
        bA[f] = *reinterpret_cast<const bf16x8*>(pwh + f * 128);

    __builtin_amdgcn_s_setprio(1);
    for (int kb = 0; kb < 24; kb += 2) {
        {
            const int o1 = (kb + 1) * 8192;
            #pragma unroll
            for (int f = 0; f < 2; ++f)
                bB[f] = *reinterpret_cast<const bf16x8*>(pwh + o1 + f * 128);
        }
        {
            const int k0 = kb * 32 + g * 8;
            const bf16x8 a0 = *reinterpret_cast<const bf16x8*>(&Ahi[rr][k0]);
            const bf16x8 a1 = *reinterpret_cast<const bf16x8*>(&Ahi[16 + rr][k0]);
            #pragma unroll
            for (int f = 0; f < 2; ++f) {
                acc[0][f] = __builtin_amdgcn_mfma_f32_16x16x32_bf16(a0, bA[f], acc[0][f], 0, 0, 0);
                acc[1][f] = __builtin_amdgcn_mfma_f32_16x16x32_bf16(a1, bA[f], acc[1][f], 0, 0, 0);
            }
        }
        if (kb + 2 < 24) {
            const int o2 = (kb + 2) * 8192;
            #pragma unroll
            for (int f = 0; f < 2; ++f)
                bA[f] = *reinterpret_cast<const bf16x8*>(pwh + o2 + f * 128);
        }
        {
            const int k0 = (kb + 1) * 32 + g * 8;
            const bf16x8 a0 = *reinterpret_cast<const bf16x8*>(&Ahi[rr][k0]);
            const bf16x8 a1 = *reinterpret_cast<const bf16x8*>(&Ahi[16 + rr][k0]);
            #pragma unroll
            for (int f = 0; f < 2; ++f) {
                acc[0][f] = __builtin_amdgcn_mfma_f32_16x16x32_bf16(a0, bB[f], acc[0][f], 0, 0, 0);
                acc[1][f] = __builtin_amdgcn_mfma_f32_16x16x32_bf16(a1, bB[f], acc[1][f], 0, 0, 0);
            }
        }
    }
    __builtin_amdgcn_s_setprio(0);

    // epilogue: D row = t*16 + g*4+i, col = colg + f*16 + rr
    float nd[2][2][4];
    #pragma unroll
    for (int t = 0; t < 2; ++t)
        #pragma unroll
        for (int f = 0; f < 2; ++f) {
            const int col = colg + f * 16 + rr;
            const float bv = bias[col];
            #pragma unroll
            for (int i = 0; i < 4; ++i) {
                const int row = t * 16 + g * 4 + i;
                const float v = fast_tanh(acc[t][f][i] + bv);
                nd[t][f][i] = v;
                if (FUSE) out_f[(size_t)(g0 + row) * 256 + col] = v;
                else      out_h[(size_t)(g0 + row) * 256 + col] = f2bf_rne(v);
            }
        }

    if (FUSE) {
        // --- attention score: per-row dot(nodes_row, a) ---
        float av[2];
        #pragma unroll
        for (int f = 0; f < 2; ++f) av[f] = attn_a[colg + f * 16 + rr];

        float s[2][4];
        #pragma unroll
        for (int t = 0; t < 2; ++t)
            #pragma unroll
            for (int i = 0; i < 4; ++i) {
                float v = 0.f;
                #pragma unroll
                for (int f = 0; f < 2; ++f) v = fmaf(nd[t][f][i], av[f], v);
                s[t][i] = v;
            }
        // reduce across the 16 rr-lanes (covers this wave's 32 cols)
        #pragma unroll
        for (int off = 1; off < 16; off <<= 1)
            #pragma unroll
            for (int t = 0; t < 2; ++t)
                #pragma unroll
                for (int i = 0; i < 4; ++i)
                    s[t][i] += __shfl_xor(s[t][i], off, 64);
        if (rr == 0) {
            #pragma unroll
            for (int t = 0; t < 2; ++t)
                #pragma unroll
                for (int i = 0; i < 4; ++i)
                    sc_lds[w][t * 16 + g * 4 + i] = s[t][i];
        }
        __syncthreads();
        if (tid < CQ) {
            float sc = 0.f;
            #pragma unroll
            for (int ww = 0; ww < 8; ++ww) sc += sc_lds[ww][tid];
            float wmv = 0.f;
            if (node_type[g0 + tid] != 0)
                wmv = __fdividef(1.f, 1.f + __expf(-sc));
            wm_lds[tid] = wmv;
        }
        __syncthreads();

        // --- weighted column-sum over the block's 32 rows ---
        float qf[2];
        #pragma unroll
        for (int f = 0; f < 2; ++f) {
            float v = 0.f;
            #pragma unroll
            for (int t = 0; t < 2; ++t)
                #pragma unroll
                for (int i = 0; i < 4; ++i)
                    v = fmaf(wm_lds[t * 16 + g * 4 + i], nd[t][f][i], v);
            qf[f] = v;
        }
        #pragma unroll
        for (int f = 0; f < 2; ++f) {
            qf[f] += __shfl_xor(qf[f], 16, 64);
            qf[f] += __shfl_xor(qf[f], 32, 64);
        }
        if (g == 0) {
            const int pidx = batch * 32 + j;
            #pragma unroll
            for (int f = 0; f < 2; ++f)
                partial[(size_t)pidx * 256 + colg + f * 16 + rr] = qf[f];
        }
    }
}

// ---------------------------------------------------------------------------
// Kernel 3: final reduce -> code_vector [16][256]
// ---------------------------------------------------------------------------
__global__ __launch_bounds__(256) void final_kernel(
    const float* __restrict__ partial, float* __restrict__ code)
{
    const int i = blockIdx.x * 256 + threadIdx.x;  // 0..4095
    const int b = i >> 8, o = i & 255;
    float acc = 0.f;
    #pragma unroll
    for (int c = 0; c < 32; ++c) acc += partial[(size_t)(b * 32 + c) * 256 + o];
    code[i] = acc * (1.f / 1024.f);
}

// ---------------------------------------------------------------------------
extern "C" void kernel_launch(void* const* d_in, const int* in_sizes, int n_in,
                              void* d_out, int out_size, void* d_ws, size_t ws_size,
                              hipStream_t stream)
{
    const int*   node_type   = (const int*)d_in[0];
    const int*   node_tokens = (const int*)d_in[1];
    const int*   children    = (const int*)d_in[2];
    const float* type_table  = (const float*)d_in[3];
    const float* token_table = (const float*)d_in[4];
    const float* Wp          = (const float*)d_in[5];
    const float* bp          = (const float*)d_in[6];
    const float* conv_w      = (const float*)d_in[7];
    const float* conv_b      = (const float*)d_in[8];
    const float* attn_a      = (const float*)d_in[9];

    float* out    = (float*)d_out;
    float* code   = out;                  // [B*O] = 4096
    float* nodesF = out + 4096;           // [BN*256] fp32 (final nodes output)

    unsigned short* nodes0 = (unsigned short*)d_ws;      // bf16 [BN*256]
    unsigned short* nodes1 = nodes0 + (size_t)BN * 256;  // bf16 [BN*256]
    float* partial = (float*)(nodes1 + (size_t)BN * 256);      // [512*256]
    unsigned short* whi = (unsigned short*)(partial + 512 * 256);  // [2][196608]
    unsigned short* wpq = whi + 2 * 196608;   // [65536]

    constexpr int LSTRIDE = 196608;           // packed shorts per layer

    pack_wp_kernel<<<32, 256, 0, stream>>>(Wp, wpq);

    emb_mfma_kernel<<<BN / EQ, 256, 0, stream>>>(
        node_type, node_tokens, type_table, token_table, wpq, bp, nodes0,
        conv_w, whi);

    conv_mfma_kernel<0><<<BN / CQ, 512, 0, stream>>>(
        nodes0, children, whi, conv_b, nodes1,
        nullptr, nullptr, nullptr, nullptr);

    conv_mfma_kernel<1><<<BN / CQ, 512, 0, stream>>>(
        nodes1, children, whi + LSTRIDE, conv_b + 256, nullptr,
        nodesF, node_type, attn_a, partial);

    final_kernel<<<16, 256, 0, stream>>>(partial, code);
}